// Round 6
// baseline (217.627 us; speedup 1.0000x reference)
//
#include <hip/hip_runtime.h>

#define N_NODES 1024
#define C_CH    128
#define N_ELEM  10
#define K3      11
#define K2      4
#define W3PM    1040   // padded symmetric-cubic floats per output slot (sum of 4*ceil((b+1)/4) over a>=b)

__global__ __launch_bounds__(512) void sym_contract_kernel(
    const float* __restrict__ node_feats,   // [N, C, 16]
    const float* __restrict__ node_attrs,   // [N, 10]
    const float* __restrict__ U03, const float* __restrict__ W03,
    const float* __restrict__ U02, const float* __restrict__ W02,
    const float* __restrict__ U01, const float* __restrict__ W01,
    const float* __restrict__ U13, const float* __restrict__ W13,
    const float* __restrict__ U12, const float* __restrict__ W12,
    const float* __restrict__ U11, const float* __restrict__ W11,
    float* __restrict__ feats_out)          // [N, C*4] pre-linear (= d_out)
{
  __shared__ float W3c[4 * W3PM];           // symmetrized cubic, zero-padded rows
  __shared__ float Dtmp[4096];              // dense scratch (T2 dense, then one cubic slice at a time)
  __shared__ float T2c[4 * 136];            // symmetrized quadratic
  __shared__ float T1s[4 * 16];
  __shared__ unsigned short nodelist[N_NODES];
  __shared__ float wrow[32];
  __shared__ int cnt;

  const int e   = blockIdx.x / C_CH;
  const int c   = blockIdx.x % C_CH;
  const int tid = threadIdx.x;

  if (tid == 0) cnt = 0;
  if (tid < 32) {
    float v;
    if (tid < 11)       v = W03[(e * K3 + tid) * C_CH + c];
    else if (tid < 15)  v = W02[(e * K2 + (tid - 11)) * C_CH + c];
    else if (tid == 15) v = W01[e * C_CH + c];
    else if (tid < 27)  v = W13[(e * K3 + (tid - 16)) * C_CH + c];
    else if (tid < 31)  v = W12[(e * K2 + (tid - 27)) * C_CH + c];
    else                v = W11[e * C_CH + c];
    wrow[tid] = v;
  }
  __syncthreads();

  // --- node list for this element ---
  for (int nd = tid; nd < N_NODES; nd += 512)
    if (node_attrs[nd * N_ELEM + e] > 0.5f)
      nodelist[atomicAdd(&cnt, 1)] = (unsigned short)nd;

  // --- dense T2 into Dtmp[0..1023] ([m][i1][i2]) ---
  for (int w = tid; w < 1024; w += 512) {
    const int mm = w >> 8, r = w & 255;
    const int wb = (mm == 0) ? 11 : 27;
    const float4 u2 = (mm == 0)
        ? *(const float4*)(U02 + r * K2)
        : *(const float4*)(U12 + ((mm - 1) * 256 + r) * K2);
    Dtmp[w] = u2.x * wrow[wb] + u2.y * wrow[wb + 1]
            + u2.z * wrow[wb + 2] + u2.w * wrow[wb + 3];
  }
  if (tid < 64) {
    const int mm = tid >> 4, i1 = tid & 15;
    T1s[tid] = (mm == 0) ? U01[i1] * wrow[15] : U11[(mm - 1) * 16 + i1] * wrow[31];
  }
  __syncthreads();

  // --- symmetrize T2: Q[a>=b] = T2[a,b] (+ T2[b,a] if a!=b) ---
  for (int t = tid; t < 544; t += 512) {
    const int s = t / 136;
    int p = t - s * 136;
    int a = 0, b = p;
    while (b > a) { b -= (a + 1); ++a; }
    const float* D2 = Dtmp + s * 256;
    T2c[t] = (a == b) ? D2[a * 16 + a] : D2[a * 16 + b] + D2[b * 16 + a];
  }

  // --- pair decompose + row offset for W3 symmetrize (hoisted, phase-A only) ---
  int pa = 0, pb = 0, poff = 0, prq = 0;
  if (tid < 136) {
    pb = tid;
    while (pb > pa) { pb -= (pa + 1); ++pa; }
    for (int aa = 0; aa < pa; ++aa)
      for (int bb = 0; bb <= aa; ++bb) poff += ((bb >> 2) + 1) << 2;
    for (int bb = 0; bb < pb; ++bb) poff += ((bb >> 2) + 1) << 2;
    prq = ((pb >> 2) + 1) << 2;
  }

  // --- per slot m: build dense cubic slice, then fold permutations ---
  for (int s = 0; s < 4; ++s) {
    __syncthreads();                         // Dtmp consumers from previous step done
    const int wb = (s == 0) ? 0 : 16;
    float wk[K3];
    #pragma unroll
    for (int k = 0; k < K3; ++k) wk[k] = wrow[wb + k];
    const float* U3 = (s == 0) ? U03 : (U13 + (size_t)(s - 1) * 4096 * K3);
    for (int w = tid; w < 4096; w += 512) {
      const float* up = U3 + (size_t)w * K3;
      float acc = 0.f;
      #pragma unroll
      for (int k = 0; k < K3; ++k) acc = fmaf(up[k], wk[k], acc);
      Dtmp[w] = acc;                         // [i1][i2][i3]
    }
    __syncthreads();
    if (tid < 136) {
      const int a = pa, b = pb;
      float* dst = W3c + s * W3PM + poff;
      for (int cc = 0; cc < prq; ++cc) {
        float v = 0.f;
        if (cc <= b) {
          if (a == b && b == cc)
            v = Dtmp[a * 256 + a * 16 + a];
          else if (a == b)
            v = Dtmp[a * 256 + a * 16 + cc] + Dtmp[a * 256 + cc * 16 + a]
              + Dtmp[cc * 256 + a * 16 + a];
          else if (b == cc)
            v = Dtmp[a * 256 + b * 16 + b] + Dtmp[b * 256 + a * 16 + b]
              + Dtmp[b * 256 + b * 16 + a];
          else
            v = Dtmp[a * 256 + b * 16 + cc] + Dtmp[a * 256 + cc * 16 + b]
              + Dtmp[b * 256 + a * 16 + cc] + Dtmp[b * 256 + cc * 16 + a]
              + Dtmp[cc * 256 + a * 16 + b] + Dtmp[cc * 256 + b * 16 + a];
        }
        dst[cc] = v;                         // zero-pad beyond b
      }
    }
  }
  __syncthreads();

  // --- phase B: lane = node; triangular Horner nest, all-broadcast LDS reads ---
  const int wave = tid >> 6;
  const int m    = wave & 3;                 // output slot
  const int grp  = wave >> 2;                // node group (0/1)
  const int lane = tid & 63;
  const float* W3m = W3c + m * W3PM;
  const float* T2m = T2c + m * 136;
  const float* T1m = T1s + m * 16;
  const int total = cnt;

  for (int base = grp * 64; base < total; base += 128) {
    const int idx     = base + lane;
    const bool active = idx < total;
    const int nd = nodelist[active ? idx : 0];
    const float* xr = node_feats + ((size_t)nd * C_CH + c) * 16;
    float xs[16];                            // static-index only -> registers
    *(float4*)&xs[0]  = ((const float4*)xr)[0];
    *(float4*)&xs[4]  = ((const float4*)xr)[1];
    *(float4*)&xs[8]  = ((const float4*)xr)[2];
    *(float4*)&xs[12] = ((const float4*)xr)[3];

    float acc = 0.f;
    int woff = 0, tp = 0;                    // unroll-folded running offsets
    #pragma unroll
    for (int a = 0; a < 16; ++a) {
      float in1 = T1m[a];
      #pragma unroll
      for (int b = 0; b <= a; ++b) {
        float in2 = T2m[tp];
        #pragma unroll
        for (int q = 0; q <= (b >> 2); ++q) {
          const float4 w4 = *(const float4*)&W3m[woff + 4 * q];   // broadcast
          in2 = fmaf(w4.x, xs[4 * q + 0], in2);
          in2 = fmaf(w4.y, xs[4 * q + 1], in2);
          in2 = fmaf(w4.z, xs[4 * q + 2], in2);
          in2 = fmaf(w4.w, xs[4 * q + 3], in2);
        }
        in1 = fmaf(in2, xs[b], in1);
        woff += ((b >> 2) + 1) << 2;
        ++tp;
      }
      acc = fmaf(in1, xs[a], acc);
    }
    if (active)
      feats_out[(size_t)nd * 512 + c * 4 + m] = acc;
  }
}

__global__ __launch_bounds__(256) void linear_kernel(
    const float* __restrict__ sc,
    const float* __restrict__ lin0,
    const float* __restrict__ lin1,
    float* __restrict__ io)             // d_out, in-place per-row
{
  __shared__ float f[512];              // [c][m]
  const int b   = blockIdx.x;
  const int tid = threadIdx.x;
  const float* row = io + (size_t)b * 512;
  if (tid < 128) ((float4*)f)[tid] = ((const float4*)row)[tid];
  __syncthreads();
  const float inv_sqrt_c = 0.088388347648318447f;   // 1/sqrt(128)
  #pragma unroll
  for (int rep = 0; rep < 2; ++rep) {
    const int o = tid + rep * 256;
    float acc = 0.f;
    if (o < 128) {
      const int fo = o;
      #pragma unroll 4
      for (int ci = 0; ci < 128; ++ci) acc = fmaf(f[ci * 4], lin0[ci * 128 + fo], acc);
    } else {
      const int oo = o - 128;
      const int fo = oo / 3;
      const int dd = oo - fo * 3;
      #pragma unroll 4
      for (int ci = 0; ci < 128; ++ci) acc = fmaf(f[ci * 4 + 1 + dd], lin1[ci * 128 + fo], acc);
    }
    io[(size_t)b * 512 + o] = fmaf(acc, inv_sqrt_c, sc[(size_t)b * 512 + o]);
  }
}

extern "C" void kernel_launch(void* const* d_in, const int* in_sizes, int n_in,
                              void* d_out, int out_size, void* d_ws, size_t ws_size,
                              hipStream_t stream) {
  const float* node_feats = (const float*)d_in[0];
  const float* sc         = (const float*)d_in[1];
  const float* node_attrs = (const float*)d_in[2];
  const float* U01  = (const float*)d_in[3];
  const float* W01  = (const float*)d_in[4];
  const float* U02  = (const float*)d_in[5];
  const float* W02  = (const float*)d_in[6];
  const float* U03  = (const float*)d_in[7];
  const float* W03  = (const float*)d_in[8];
  const float* lin0 = (const float*)d_in[9];
  const float* U11  = (const float*)d_in[10];
  const float* W11  = (const float*)d_in[11];
  const float* U12  = (const float*)d_in[12];
  const float* W12  = (const float*)d_in[13];
  const float* U13  = (const float*)d_in[14];
  const float* W13  = (const float*)d_in[15];
  const float* lin1 = (const float*)d_in[16];
  float* out = (float*)d_out;

  sym_contract_kernel<<<N_ELEM * C_CH, 512, 0, stream>>>(
      node_feats, node_attrs,
      U03, W03, U02, W02, U01, W01,
      U13, W13, U12, W12, U11, W11, out);
  linear_kernel<<<N_NODES, 256, 0, stream>>>(sc, lin0, lin1, out);
}

// Round 7
// 180.987 us; speedup vs baseline: 1.2024x; 1.2024x over previous
//
#include <hip/hip_runtime.h>

#define N_NODES 1024
#define C_CH    128
#define N_ELEM  10
#define K3      11
#define K2      4
#define W3PM    1040   // padded symmetric-cubic floats per output slot
#define DIDX(A,B,CV) ((A) * 272 + (B) * 17 + (CV))   // bank-spread dense layout

__global__ __launch_bounds__(512) void sym_contract_kernel(
    const float* __restrict__ node_feats,   // [N, C, 16]
    const float* __restrict__ node_attrs,   // [N, 10]
    const float* __restrict__ U03, const float* __restrict__ W03,
    const float* __restrict__ U02, const float* __restrict__ W02,
    const float* __restrict__ U01, const float* __restrict__ W01,
    const float* __restrict__ U13, const float* __restrict__ W13,
    const float* __restrict__ U12, const float* __restrict__ W12,
    const float* __restrict__ U11, const float* __restrict__ W11,
    float* __restrict__ feats_out)          // [N, C*4] pre-linear (= d_out)
{
  __shared__ float W3c[4 * W3PM];           // symmetrized cubic, zero-padded rows
  __shared__ float Dtmp[4352];              // dense scratch, padded layout
  __shared__ float T2c[4 * 136];            // symmetrized quadratic
  __shared__ float T1s[4 * 16];
  __shared__ unsigned short nodelist[N_NODES];
  __shared__ float wrow[32];
  __shared__ unsigned int lutP[136];        // pa<<24 | pb<<20 | poff
  __shared__ int cnt;

  const int e   = blockIdx.x / C_CH;
  const int c   = blockIdx.x % C_CH;
  const int tid = threadIdx.x;

  if (tid == 0) cnt = 0;
  if (tid < 32) {
    float v;
    if (tid < 11)       v = W03[(e * K3 + tid) * C_CH + c];
    else if (tid < 15)  v = W02[(e * K2 + (tid - 11)) * C_CH + c];
    else if (tid == 15) v = W01[e * C_CH + c];
    else if (tid < 27)  v = W13[(e * K3 + (tid - 16)) * C_CH + c];
    else if (tid < 31)  v = W12[(e * K2 + (tid - 27)) * C_CH + c];
    else                v = W11[e * C_CH + c];
    wrow[tid] = v;
  }
  __syncthreads();

  // --- node list for this element ---
  for (int nd = tid; nd < N_NODES; nd += 512)
    if (node_attrs[nd * N_ELEM + e] > 0.5f)
      nodelist[atomicAdd(&cnt, 1)] = (unsigned short)nd;

  // --- pair LUT (one-time): (a,b) decompose + padded row offset ---
  if (tid < 136) {
    int a = 0, b = tid;
    while (b > a) { b -= (a + 1); ++a; }
    int off = 0;
    for (int aa = 0; aa < a; ++aa)
      for (int bb = 0; bb <= aa; ++bb) off += ((bb >> 2) + 1) << 2;
    for (int bb = 0; bb < b; ++bb) off += ((bb >> 2) + 1) << 2;
    lutP[tid] = ((unsigned)a << 24) | ((unsigned)b << 20) | (unsigned)off;
  }

  // --- dense T2 into Dtmp[0..1023] ([m][i1][i2], plain layout) ---
  for (int w = tid; w < 1024; w += 512) {
    const int mm = w >> 8, r = w & 255;
    const int wb = (mm == 0) ? 11 : 27;
    const float4 u2 = (mm == 0)
        ? *(const float4*)(U02 + r * K2)
        : *(const float4*)(U12 + ((mm - 1) * 256 + r) * K2);
    Dtmp[w] = u2.x * wrow[wb] + u2.y * wrow[wb + 1]
            + u2.z * wrow[wb + 2] + u2.w * wrow[wb + 3];
  }
  if (tid < 64) {
    const int mm = tid >> 4, i1 = tid & 15;
    T1s[tid] = (mm == 0) ? U01[i1] * wrow[15] : U11[(mm - 1) * 16 + i1] * wrow[31];
  }
  __syncthreads();

  // --- symmetrize T2: Q[a>=b] = T2[a,b] (+ T2[b,a] if a!=b) ---
  for (int t = tid; t < 544; t += 512) {
    const int s = t / 136;
    const int p = t - s * 136;
    const unsigned u = lutP[p];
    const int a = u >> 24, b = (u >> 20) & 15;
    const float* D2 = Dtmp + s * 256;
    T2c[t] = (a == b) ? D2[a * 16 + a] : D2[a * 16 + b] + D2[b * 16 + a];
  }

  // --- per slot m: build dense cubic slice (padded), then fold permutations ---
  for (int s = 0; s < 4; ++s) {
    __syncthreads();                         // previous Dtmp consumers done
    const int wb = (s == 0) ? 0 : 16;
    float wk[K3];
    #pragma unroll
    for (int k = 0; k < K3; ++k) wk[k] = wrow[wb + k];
    const float* U3 = (s == 0) ? U03 : (U13 + (size_t)(s - 1) * 4096 * K3);
    for (int w = tid; w < 4096; w += 512) {
      const float* up = U3 + (size_t)w * K3;
      float acc = 0.f;
      #pragma unroll
      for (int k = 0; k < K3; ++k) acc = fmaf(up[k], wk[k], acc);
      const int i1 = w >> 8, rem = w & 255;
      Dtmp[DIDX(i1, rem >> 4, rem & 15)] = acc;
    }
    __syncthreads();
    // work-item = (pair p, cc) -> all 512 threads, conflict-free rows
    for (int t = tid; t < 136 * 16; t += 512) {
      const int p  = t >> 4;
      const int cc = t & 15;
      const unsigned u = lutP[p];
      const int a = u >> 24, b = (u >> 20) & 15;
      const int off = u & 0xFFFFF;
      const int prq = ((b >> 2) + 1) << 2;
      if (cc < prq) {
        float v = 0.f;
        if (cc <= b) {
          if (a == b && b == cc)
            v = Dtmp[DIDX(a, a, a)];
          else if (a == b)
            v = Dtmp[DIDX(a, a, cc)] + Dtmp[DIDX(a, cc, a)] + Dtmp[DIDX(cc, a, a)];
          else if (b == cc)
            v = Dtmp[DIDX(a, b, b)] + Dtmp[DIDX(b, a, b)] + Dtmp[DIDX(b, b, a)];
          else
            v = Dtmp[DIDX(a, b, cc)] + Dtmp[DIDX(a, cc, b)] + Dtmp[DIDX(b, a, cc)]
              + Dtmp[DIDX(b, cc, a)] + Dtmp[DIDX(cc, a, b)] + Dtmp[DIDX(cc, b, a)];
        }
        W3c[s * W3PM + off + cc] = v;        // zero-pad beyond b
      }
    }
  }
  __syncthreads();

  // --- phase B: lane = node; triangular Horner nest, all-broadcast LDS reads ---
  const int wave = tid >> 6;
  const int m    = wave & 3;                 // output slot
  const int grp  = wave >> 2;                // node group (0/1)
  const int lane = tid & 63;
  const float* W3m = W3c + m * W3PM;
  const float* T2m = T2c + m * 136;
  const float* T1m = T1s + m * 16;
  const int total = cnt;

  for (int base = grp * 64; base < total; base += 128) {
    const int idx     = base + lane;
    const bool active = idx < total;
    const int nd = nodelist[active ? idx : 0];
    const float* xr = node_feats + ((size_t)nd * C_CH + c) * 16;
    float xs[16];                            // static-index only -> registers
    *(float4*)&xs[0]  = ((const float4*)xr)[0];
    *(float4*)&xs[4]  = ((const float4*)xr)[1];
    *(float4*)&xs[8]  = ((const float4*)xr)[2];
    *(float4*)&xs[12] = ((const float4*)xr)[3];

    float acc = 0.f;
    int woff = 0, tp = 0;                    // unroll-folded running offsets
    #pragma unroll
    for (int a = 0; a < 16; ++a) {
      float in1 = T1m[a];
      #pragma unroll
      for (int b = 0; b <= a; ++b) {
        float in2 = T2m[tp];
        #pragma unroll
        for (int q = 0; q <= (b >> 2); ++q) {
          const float4 w4 = *(const float4*)&W3m[woff + 4 * q];   // broadcast
          in2 = fmaf(w4.x, xs[4 * q + 0], in2);
          in2 = fmaf(w4.y, xs[4 * q + 1], in2);
          in2 = fmaf(w4.z, xs[4 * q + 2], in2);
          in2 = fmaf(w4.w, xs[4 * q + 3], in2);
        }
        in1 = fmaf(in2, xs[b], in1);
        woff += ((b >> 2) + 1) << 2;
        ++tp;
      }
      acc = fmaf(in1, xs[a], acc);
    }
    if (active)
      feats_out[(size_t)nd * 512 + c * 4 + m] = acc;
  }
}

__global__ __launch_bounds__(256) void linear_kernel(
    const float* __restrict__ sc,
    const float* __restrict__ lin0,
    const float* __restrict__ lin1,
    float* __restrict__ io)             // d_out, in-place per-row
{
  __shared__ float f[512];              // [c][m]
  const int b   = blockIdx.x;
  const int tid = threadIdx.x;
  const float* row = io + (size_t)b * 512;
  if (tid < 128) ((float4*)f)[tid] = ((const float4*)row)[tid];
  __syncthreads();
  const float inv_sqrt_c = 0.088388347648318447f;   // 1/sqrt(128)
  #pragma unroll
  for (int rep = 0; rep < 2; ++rep) {
    const int o = tid + rep * 256;
    float acc = 0.f;
    if (o < 128) {
      const int fo = o;
      #pragma unroll 4
      for (int ci = 0; ci < 128; ++ci) acc = fmaf(f[ci * 4], lin0[ci * 128 + fo], acc);
    } else {
      const int oo = o - 128;
      const int fo = oo / 3;
      const int dd = oo - fo * 3;
      #pragma unroll 4
      for (int ci = 0; ci < 128; ++ci) acc = fmaf(f[ci * 4 + 1 + dd], lin1[ci * 128 + fo], acc);
    }
    io[(size_t)b * 512 + o] = fmaf(acc, inv_sqrt_c, sc[(size_t)b * 512 + o]);
  }
}

extern "C" void kernel_launch(void* const* d_in, const int* in_sizes, int n_in,
                              void* d_out, int out_size, void* d_ws, size_t ws_size,
                              hipStream_t stream) {
  const float* node_feats = (const float*)d_in[0];
  const float* sc         = (const float*)d_in[1];
  const float* node_attrs = (const float*)d_in[2];
  const float* U01  = (const float*)d_in[3];
  const float* W01  = (const float*)d_in[4];
  const float* U02  = (const float*)d_in[5];
  const float* W02  = (const float*)d_in[6];
  const float* U03  = (const float*)d_in[7];
  const float* W03  = (const float*)d_in[8];
  const float* lin0 = (const float*)d_in[9];
  const float* U11  = (const float*)d_in[10];
  const float* W11  = (const float*)d_in[11];
  const float* U12  = (const float*)d_in[12];
  const float* W12  = (const float*)d_in[13];
  const float* U13  = (const float*)d_in[14];
  const float* W13  = (const float*)d_in[15];
  const float* lin1 = (const float*)d_in[16];
  float* out = (float*)d_out;

  sym_contract_kernel<<<N_ELEM * C_CH, 512, 0, stream>>>(
      node_feats, node_attrs,
      U03, W03, U02, W02, U01, W01,
      U13, W13, U12, W12, U11, W11, out);
  linear_kernel<<<N_NODES, 256, 0, stream>>>(sc, lin0, lin1, out);
}